// Round 13
// baseline (175.389 us; speedup 1.0000x reference)
//
#include <hip/hip_runtime.h>
#include <hip/hip_bf16.h>
#include <math.h>

// Problem constants
#define B    8
#define C4   64
#define CQ   16
#define NN   512
#define L4   12
#define NCH1 8            // n's per k1 block
#define KT   128          // k-tile in final kernel

// workspace layout (float offsets)
#define O_TH   0                                   // Thi bf16 [b][m][n]      2097152
#define O_TL   (O_TH + (size_t)B*1024*NN/2)        // Tlo bf16 [b][m][n]      2097152
#define O_T2H  (O_TL + (size_t)B*1024*NN/2)        // Thi bf16 [b][n][m]      2097152
#define O_T2L  (O_T2H + (size_t)B*NN*1024/2)       // Tlo bf16 [b][n][m]      2097152
#define O_FL   (O_T2L + (size_t)B*NN*1024/2)       // Fl[b][q][k] fp32          65536
#define O_FLTH (O_FL + (size_t)B*CQ*NN)            // Flt hi bf16 [b][k][16]    32768
#define O_FLTL (O_FLTH + (size_t)B*NN*16/2)        // Flt lo bf16 [b][k][16]    32768
#define O_XX   (O_FLTL + (size_t)B*NN*16/2)        // [B][CQ]                     128
#define O_YY   (O_XX + B*CQ)                       //                             128
#define O_L2   (O_YY + B*CQ)                       // [B] 1/l2 (+pad)              16
#define O_AH   (O_L2 + 16)                         // Ahi bf16 [b][n][k]      1048576
#define O_AL   (O_AH + (size_t)B*NN*NN/2)          // Alo bf16 [b][n][k]      1048576
#define O_XGP  (O_AL + (size_t)B*NN*NN/2)          // xg partials [b][2][c][k] 524288

typedef __attribute__((ext_vector_type(8))) short short8;
typedef __attribute__((ext_vector_type(4))) float floatx4;
typedef __attribute__((ext_vector_type(16))) float floatx16;

__device__ inline void split2(float x0, float x1, uint& hw, uint& lw) {
  uint u0 = __float_as_uint(x0), u1 = __float_as_uint(x1);
  uint h0 = u0 >> 16, h1 = u1 >> 16;
  float r0 = x0 - __uint_as_float(h0 << 16);
  float r1 = x1 - __uint_as_float(h1 << 16);
  hw = h0 | (h1 << 16);
  lw = (__float_as_uint(r0) >> 16) | ((__float_as_uint(r1) >> 16) << 16);
}

// K1: Fc, Fl, norms, T bf16 split planes in BOTH layouts:
//  TH/TL [m][n] (for k3 A-frags), T2H/T2L [n][m] (for k2 A-frags).
__global__ __launch_bounds__(256) void k1_fc(const float* __restrict__ x,
                                             const float* __restrict__ Wc,
                                             const float* __restrict__ bc,
                                             float* __restrict__ ws) {
  int blk = blockIdx.x;                // b*64 + nchunk
  int b = blk >> 6;
  int n0 = (blk & 63) * NCH1;
  int t = threadIdx.x;
  __shared__ __align__(16) float xs[C4*NCH1*L4];   // [c][nl*12+j] 6144
  __shared__ float wcs[CQ*65];                     // [q][c] padded (bank fix)
  __shared__ float bcs[CQ];
  __shared__ __align__(16) float fcs[NCH1*CQ*L4];  // [nl][q][j] 1536

  for (int e = t; e < CQ*C4; e += 256) {
    int q = e >> 6, c = e & 63;
    wcs[q*65 + c] = Wc[e];
  }
  if (t < CQ) bcs[t] = bc[t];
  const float* xb = x + (size_t)b*C4*NN*L4 + (size_t)n0*L4;
  for (int f = t; f < (C4*NCH1*L4)/4; f += 256) {
    int c = f / (NCH1*L4/4);
    int r = f - c*(NCH1*L4/4);
    float4 v = *(const float4*)(xb + (size_t)c*NN*L4 + r*4);
    *(float4*)(xs + c*(NCH1*L4) + r*4) = v;
  }
  __syncthreads();
  // Fc: thread owns q = t&15, slots nj = (t>>4) + 16*i (i<6); 1 wcs read/c.
  {
    int q = t & 15, slot = t >> 4;
    float accv[6];
    #pragma unroll
    for (int i = 0; i < 6; ++i) accv[i] = bcs[q];
    for (int c = 0; c < C4; ++c) {
      float wv = wcs[q*65 + c];
      const float* xc = xs + c*(NCH1*L4);
      #pragma unroll
      for (int i = 0; i < 6; ++i) accv[i] += wv * xc[slot + 16*i];
    }
    #pragma unroll
    for (int i = 0; i < 6; ++i) {
      int nj = slot + 16*i;
      int nl = nj / L4, j = nj - nl*L4;
      fcs[nl*(CQ*L4) + q*L4 + j] = accv[i];
      if (j == L4-1) ws[O_FL + ((size_t)b*CQ + q)*NN + n0 + nl] = accv[i];
    }
  }
  __syncthreads();
  if (t < CQ) {
    float yy = 0.f, xx = 0.f;
    for (int nl = 0; nl < NCH1; ++nl) {
      #pragma unroll
      for (int j = 0; j < L4; ++j) { float v = fcs[nl*(CQ*L4) + t*L4 + j]; yy += v*v; }
      float w = fcs[nl*(CQ*L4) + t*L4 + (L4-1)];
      xx += w*w;
    }
    atomicAdd(ws + O_YY + b*CQ + t, yy);
    atomicAdd(ws + O_XX + b*CQ + t, xx);
  }
  {
    int c = t >> 2, q0 = (t & 3) * 4;
    float vals[4][NCH1];
    ushort* T2H = (ushort*)(ws + O_T2H);
    ushort* T2L = (ushort*)(ws + O_T2L);
    for (int nl = 0; nl < NCH1; ++nl) {
      float xr[L4];
      *(float4*)&xr[0] = *(const float4*)(xs + c*(NCH1*L4) + nl*L4);
      *(float4*)&xr[4] = *(const float4*)(xs + c*(NCH1*L4) + nl*L4 + 4);
      *(float4*)&xr[8] = *(const float4*)(xs + c*(NCH1*L4) + nl*L4 + 8);
      float tvp[4];
      #pragma unroll
      for (int i = 0; i < 4; ++i) {
        float a = 0.f;
        #pragma unroll
        for (int j = 0; j < L4; ++j) a += fcs[nl*(CQ*L4) + (q0+i)*L4 + j] * xr[j];
        tvp[i] = a;
        vals[i][nl] = a;
      }
      uint hw0, lw0, hw1, lw1;
      split2(tvp[0], tvp[1], hw0, lw0);
      split2(tvp[2], tvp[3], hw1, lw1);
      size_t off2 = ((size_t)b*NN + n0 + nl)*1024 + t*4;   // ushort index
      *(uint2*)(T2H + off2) = make_uint2(hw0, hw1);
      *(uint2*)(T2L + off2) = make_uint2(lw0, lw1);
    }
    ushort* TH = (ushort*)(ws + O_TH);
    ushort* TL = (ushort*)(ws + O_TL);
    #pragma unroll
    for (int i = 0; i < 4; ++i) {
      int m = c*16 + q0 + i;
      uint hw[4], lw[4];
      #pragma unroll
      for (int jj = 0; jj < 4; ++jj)
        split2(vals[i][2*jj], vals[i][2*jj+1], hw[jj], lw[jj]);
      size_t off = ((size_t)b*1024 + m)*NN + n0;   // ushort index
      *(uint4*)(TH + off) = make_uint4(hw[0], hw[1], hw[2], hw[3]);
      *(uint4*)(TL + off) = make_uint4(lw[0], lw[1], lw[2], lw[3]);
    }
  }
}

// K1b (merged): block 0 computes l2inv; all 16 blocks convert Flt planes.
__global__ __launch_bounds__(256) void k1b_l2flt(float* __restrict__ ws) {
  int t = threadIdx.x;
  if (blockIdx.x == 0 && t < B*CQ) {
    __shared__ float s[B*CQ];
    s[t] = sqrtf(ws[O_XX + t]) * sqrtf(ws[O_YY + t]);
    __syncthreads();
    if (t < B) {
      float sum = 0.f;
      #pragma unroll
      for (int q = 0; q < CQ; ++q) sum += s[t*CQ + q];
      ws[O_L2 + t] = 1.0f / sum;
    }
  } else if (blockIdx.x == 0) {
    __syncthreads();   // keep barrier convergent for block 0
  }
  int idx = blockIdx.x*256 + t;             // 0..4095 = b*512 + k
  int b = idx >> 9, k = idx & 511;
  const float* fl = ws + O_FL + (size_t)b*CQ*NN + k;
  ushort h[16], l[16];
  #pragma unroll
  for (int q = 0; q < CQ; ++q) {
    float v = fl[(size_t)q*NN];
    uint u = __float_as_uint(v);
    uint hh = u >> 16;
    float r = v - __uint_as_float(hh << 16);
    h[q] = (ushort)hh;
    l[q] = (ushort)(__float_as_uint(r) >> 16);
  }
  ushort* FH  = (ushort*)(ws + O_FLTH) + (size_t)idx*16;
  ushort* FLo = (ushort*)(ws + O_FLTL) + (size_t)idx*16;
  *(uint4*)(FH)      = *(uint4*)&h[0];
  *(uint4*)(FH + 8)  = *(uint4*)&h[8];
  *(uint4*)(FLo)     = *(uint4*)&l[0];
  *(uint4*)(FLo + 8) = *(uint4*)&l[8];
}

// K2 (pass 1, MFMA 32x32x16 split-bf16): unchanged from R11 (passed).
__global__ __launch_bounds__(256, 4) void k2_mfma(float* __restrict__ ws) {
  int id = blockIdx.x;              // b*128 + nch*2 + kh
  int kh = id & 1;
  int nch = (id >> 1) & 63;
  int b = id >> 7;
  int t = threadIdx.x;
  int w = t >> 6, lane = t & 63;
  int col = lane & 31, half = lane >> 5;
  float l2inv = ws[O_L2 + b];
  const ushort* FltH = (const ushort*)(ws + O_FLTH);
  const ushort* FltL = (const ushort*)(ws + O_FLTL);
  short8 bhf[2], blf[2];
  int kcol[2];
  #pragma unroll
  for (int kt = 0; kt < 2; ++kt) {
    kcol[kt] = kh*256 + w*64 + kt*32 + col;
    size_t off = ((size_t)(b*NN + kcol[kt]))*16 + half*8;
    bhf[kt] = *(const short8*)(FltH + off);
    blf[kt] = *(const short8*)(FltL + off);
  }
  const ushort* T2H = (const ushort*)(ws + O_T2H) + ((size_t)b*NN + nch*8)*1024;
  const ushort* T2L = (const ushort*)(ws + O_T2L) + ((size_t)b*NN + nch*8)*1024;
  ushort* AH = (ushort*)(ws + O_AH) + ((size_t)b*NN + nch*8)*NN;
  ushort* AL = (ushort*)(ws + O_AL) + ((size_t)b*NN + nch*8)*NN;

  for (int i = 0; i < 8; ++i) {
    short8 ah[2], al[2];
    #pragma unroll
    for (int ct = 0; ct < 2; ++ct) {
      size_t off = (size_t)i*1024 + (ct*32 + col)*16 + half*8;
      ah[ct] = *(const short8*)(T2H + off);
      al[ct] = *(const short8*)(T2L + off);
    }
    floatx16 acc[2][2];
    #pragma unroll
    for (int ct = 0; ct < 2; ++ct)
      #pragma unroll
      for (int kt = 0; kt < 2; ++kt) {
        floatx16 a = {0.f,0.f,0.f,0.f,0.f,0.f,0.f,0.f,
                      0.f,0.f,0.f,0.f,0.f,0.f,0.f,0.f};
        a = __builtin_amdgcn_mfma_f32_32x32x16_bf16(ah[ct], bhf[kt], a, 0, 0, 0);
        a = __builtin_amdgcn_mfma_f32_32x32x16_bf16(ah[ct], blf[kt], a, 0, 0, 0);
        a = __builtin_amdgcn_mfma_f32_32x32x16_bf16(al[ct], bhf[kt], a, 0, 0, 0);
        acc[ct][kt] = a;
      }
    #pragma unroll
    for (int kt = 0; kt < 2; ++kt) {
      float m = acc[0][kt][0];
      #pragma unroll
      for (int ct = 0; ct < 2; ++ct)
        #pragma unroll
        for (int rg = 0; rg < 16; ++rg)
          if (ct + rg) m = fmaxf(m, acc[ct][kt][rg]);
      m = fmaxf(m, __shfl_xor(m, 32));
      float av = fmaxf(tanhf(m*l2inv), 0.f);
      uint u = __float_as_uint(av);
      uint hh = u >> 16;
      float r = av - __uint_as_float(hh << 16);
      ushort lv = (ushort)(__float_as_uint(r) >> 16);
      if (half == 0) {
        AH[(size_t)i*NN + kcol[kt]] = (ushort)hh;
        AL[(size_t)i*NN + kcol[kt]] = lv;
      }
    }
  }
}

// K3 (pass 2, MFMA split-bf16, LDS-FREE): fragments loaded directly from
// global (identical addresses to the previously-staged tiles; both A and B
// frags are 8 contiguous ushorts). No barriers — waves fully independent.
__global__ __launch_bounds__(256, 4) void k3_mfma(float* __restrict__ ws) {
  int id = blockIdx.x;             // b*128 + ns*64 + mbb*8 + kb
  int kb = id & 7;
  int mbb = (id >> 3) & 7;
  int ns = (id >> 6) & 1;
  int b = id >> 7;
  int t = threadIdx.x;
  int lane = t & 63;
  int w = t >> 6;
  int mw = w >> 1, kw = w & 1;
  int row = lane & 15, quad = lane >> 4;

  const ushort* TH = (const ushort*)(ws + O_TH) + ((size_t)b*1024 + mbb*128)*NN;
  const ushort* TL = (const ushort*)(ws + O_TL) + ((size_t)b*1024 + mbb*128)*NN;
  const ushort* AHp = (const ushort*)(ws + O_AH) + ((size_t)b*NN + kb*64)*NN;
  const ushort* ALp = (const ushort*)(ws + O_AL) + ((size_t)b*NN + kb*64)*NN;

  floatx4 acc[4][2];
  #pragma unroll
  for (int i = 0; i < 4; ++i)
    #pragma unroll
    for (int j = 0; j < 2; ++j) acc[i][j] = (floatx4){0.f, 0.f, 0.f, 0.f};

  for (int ksx = 0; ksx < 8; ++ksx) {
    int p0 = ns*256 + ksx*32 + quad*8;
    short8 bh[2], bl[2];
    #pragma unroll
    for (int kt = 0; kt < 2; ++kt) {
      size_t off = (size_t)(kw*32 + kt*16 + row)*NN + p0;
      bh[kt] = *(const short8*)(AHp + off);
      bl[kt] = *(const short8*)(ALp + off);
    }
    #pragma unroll
    for (int mt = 0; mt < 4; ++mt) {
      size_t off = (size_t)(mw*64 + mt*16 + row)*NN + p0;
      short8 ah = *(const short8*)(TH + off);
      short8 al = *(const short8*)(TL + off);
      #pragma unroll
      for (int kt = 0; kt < 2; ++kt) {
        acc[mt][kt] = __builtin_amdgcn_mfma_f32_16x16x32_bf16(ah, bh[kt], acc[mt][kt], 0, 0, 0);
        acc[mt][kt] = __builtin_amdgcn_mfma_f32_16x16x32_bf16(ah, bl[kt], acc[mt][kt], 0, 0, 0);
        acc[mt][kt] = __builtin_amdgcn_mfma_f32_16x16x32_bf16(al, bh[kt], acc[mt][kt], 0, 0, 0);
      }
    }
  }
  float l2inv = ws[O_L2 + b];
  const float* flb = ws + O_FL + (size_t)b*CQ*NN;
  float fl[2][4];
  #pragma unroll
  for (int kt = 0; kt < 2; ++kt) {
    int kcol = kb*64 + kw*32 + kt*16 + row;
    #pragma unroll
    for (int rg = 0; rg < 4; ++rg)
      fl[kt][rg] = flb[(size_t)(quad*4 + rg)*NN + kcol];
  }
  #pragma unroll
  for (int mt = 0; mt < 4; ++mt) {
    int c = mbb*8 + mw*4 + mt;
    #pragma unroll
    for (int kt = 0; kt < 2; ++kt) {
      float s = fl[kt][0]*acc[mt][kt][0] + fl[kt][1]*acc[mt][kt][1]
              + fl[kt][2]*acc[mt][kt][2] + fl[kt][3]*acc[mt][kt][3];
      s += __shfl_xor(s, 32);
      s += __shfl_xor(s, 16);
      if (quad == 0) {
        int kcol = kb*64 + kw*32 + kt*16 + row;
        ws[O_XGP + (((size_t)(b*2 + ns)*C4 + c)*NN) + kcol] = s * l2inv;
      }
    }
  }
}

// K4: sum 2 n-split partials, then Fg = W_gcn xg + b_gcn
__global__ __launch_bounds__(256) void k4_out(const float* __restrict__ Wg,
                                              const float* __restrict__ bg,
                                              const float* __restrict__ ws,
                                              float* __restrict__ out) {
  int blk = blockIdx.x;             // b*4 + kc
  int b = blk >> 2, kc = blk & 3;
  int t = threadIdx.x;
  __shared__ float xg[C4][KT+1];
  __shared__ float wg[C4*C4];
  for (int e = t; e < C4*C4; e += 256) wg[e] = Wg[e];
  for (int e = t; e < C4*KT; e += 256) {
    int c = e >> 7, kk = e & (KT-1);
    xg[c][kk] = ws[O_XGP + (((size_t)(b*2 + 0)*C4 + c)*NN) + kc*KT + kk]
              + ws[O_XGP + (((size_t)(b*2 + 1)*C4 + c)*NN) + kc*KT + kk];
  }
  __syncthreads();
  int kk = t & (KT-1);
  int ohalf = t >> 7;
  for (int oi = 0; oi < 32; ++oi) {
    int o = ohalf*32 + oi;
    float acc = bg[o];
    #pragma unroll
    for (int c = 0; c < C4; ++c) acc += wg[o*C4 + c] * xg[c][kk];
    out[((size_t)(b*C4 + o))*NN + kc*KT + kk] = acc;
  }
}

extern "C" void kernel_launch(void* const* d_in, const int* in_sizes, int n_in,
                              void* d_out, int out_size, void* d_ws, size_t ws_size,
                              hipStream_t stream) {
  const float* x  = (const float*)d_in[0];
  const float* Wc = (const float*)d_in[1];
  const float* bc = (const float*)d_in[2];
  const float* Wg = (const float*)d_in[3];
  const float* bg = (const float*)d_in[4];
  float* ws  = (float*)d_ws;
  float* out = (float*)d_out;

  hipMemsetAsync(ws + O_XX, 0, (2*B*CQ + 16)*sizeof(float), stream);

  k1_fc    <<<B*64,   256, 0, stream>>>(x, Wc, bc, ws);
  k1b_l2flt<<<16,     256, 0, stream>>>(ws);
  k2_mfma  <<<B*128,  256, 0, stream>>>(ws);
  k3_mfma  <<<B*128,  256, 0, stream>>>(ws);
  k4_out   <<<B*4,    256, 0, stream>>>(Wg, bg, ws, out);
}

// Round 14
// 153.734 us; speedup vs baseline: 1.1409x; 1.1409x over previous
//
#include <hip/hip_runtime.h>
#include <hip/hip_bf16.h>
#include <math.h>

// Problem constants
#define B    8
#define C4   64
#define CQ   16
#define NN   512
#define L4   12
#define NCH1 8            // n's per k1 block
#define KT   128          // k-tile in final kernel

// workspace layout (float offsets)
#define O_TH   0                                   // Thi bf16 [b][m][n]      2097152
#define O_TL   (O_TH + (size_t)B*1024*NN/2)        // Tlo bf16 [b][m][n]      2097152
#define O_T2H  (O_TL + (size_t)B*1024*NN/2)        // Thi bf16 [b][n][m]      2097152
#define O_T2L  (O_T2H + (size_t)B*NN*1024/2)       // Tlo bf16 [b][n][m]      2097152
#define O_FL   (O_T2L + (size_t)B*NN*1024/2)       // Fl[b][q][k] fp32          65536
#define O_FLTH (O_FL + (size_t)B*CQ*NN)            // Flt hi bf16 [b][k][16]    32768
#define O_FLTL (O_FLTH + (size_t)B*NN*16/2)        // Flt lo bf16 [b][k][16]    32768
#define O_XX   (O_FLTL + (size_t)B*NN*16/2)        // [B][CQ]                     128
#define O_YY   (O_XX + B*CQ)                       //                             128
#define O_L2   (O_YY + B*CQ)                       // [B] 1/l2 (+pad)              16
#define O_AH   (O_L2 + 16)                         // Ahi bf16 [b][n][k]      1048576
#define O_AL   (O_AH + (size_t)B*NN*NN/2)          // Alo bf16 [b][n][k]      1048576
#define O_XG   (O_AL + (size_t)B*NN*NN/2)          // xg[b][c][k] fp32         262144

typedef __attribute__((ext_vector_type(8))) short short8;
typedef __attribute__((ext_vector_type(4))) float floatx4;
typedef __attribute__((ext_vector_type(16))) float floatx16;

__device__ inline void split2(float x0, float x1, uint& hw, uint& lw) {
  uint u0 = __float_as_uint(x0), u1 = __float_as_uint(x1);
  uint h0 = u0 >> 16, h1 = u1 >> 16;
  float r0 = x0 - __uint_as_float(h0 << 16);
  float r1 = x1 - __uint_as_float(h1 << 16);
  hw = h0 | (h1 << 16);
  lw = (__float_as_uint(r0) >> 16) | ((__float_as_uint(r1) >> 16) << 16);
}

// K1: Fc, Fl, norms, T bf16 split planes in BOTH layouts:
//  TH/TL [m][n] (for k3 A-frags), T2H/T2L [n][m] (for k2 A-frags).
__global__ __launch_bounds__(256) void k1_fc(const float* __restrict__ x,
                                             const float* __restrict__ Wc,
                                             const float* __restrict__ bc,
                                             float* __restrict__ ws) {
  int blk = blockIdx.x;                // b*64 + nchunk
  int b = blk >> 6;
  int n0 = (blk & 63) * NCH1;
  int t = threadIdx.x;
  __shared__ __align__(16) float xs[C4*NCH1*L4];   // [c][nl*12+j] 6144
  __shared__ float wcs[CQ*65];                     // [q][c] padded (bank fix)
  __shared__ float bcs[CQ];
  __shared__ __align__(16) float fcs[NCH1*CQ*L4];  // [nl][q][j] 1536

  for (int e = t; e < CQ*C4; e += 256) {
    int q = e >> 6, c = e & 63;
    wcs[q*65 + c] = Wc[e];
  }
  if (t < CQ) bcs[t] = bc[t];
  const float* xb = x + (size_t)b*C4*NN*L4 + (size_t)n0*L4;
  for (int f = t; f < (C4*NCH1*L4)/4; f += 256) {
    int c = f / (NCH1*L4/4);
    int r = f - c*(NCH1*L4/4);
    float4 v = *(const float4*)(xb + (size_t)c*NN*L4 + r*4);
    *(float4*)(xs + c*(NCH1*L4) + r*4) = v;
  }
  __syncthreads();
  // Fc: thread owns q = t&15, slots nj = (t>>4) + 16*i (i<6); 1 wcs read/c.
  {
    int q = t & 15, slot = t >> 4;
    float accv[6];
    #pragma unroll
    for (int i = 0; i < 6; ++i) accv[i] = bcs[q];
    for (int c = 0; c < C4; ++c) {
      float wv = wcs[q*65 + c];
      const float* xc = xs + c*(NCH1*L4);
      #pragma unroll
      for (int i = 0; i < 6; ++i) accv[i] += wv * xc[slot + 16*i];
    }
    #pragma unroll
    for (int i = 0; i < 6; ++i) {
      int nj = slot + 16*i;
      int nl = nj / L4, j = nj - nl*L4;
      fcs[nl*(CQ*L4) + q*L4 + j] = accv[i];
      if (j == L4-1) ws[O_FL + ((size_t)b*CQ + q)*NN + n0 + nl] = accv[i];
    }
  }
  __syncthreads();
  if (t < CQ) {
    float yy = 0.f, xx = 0.f;
    for (int nl = 0; nl < NCH1; ++nl) {
      #pragma unroll
      for (int j = 0; j < L4; ++j) { float v = fcs[nl*(CQ*L4) + t*L4 + j]; yy += v*v; }
      float w = fcs[nl*(CQ*L4) + t*L4 + (L4-1)];
      xx += w*w;
    }
    atomicAdd(ws + O_YY + b*CQ + t, yy);
    atomicAdd(ws + O_XX + b*CQ + t, xx);
  }
  {
    int c = t >> 2, q0 = (t & 3) * 4;
    float vals[4][NCH1];
    ushort* T2H = (ushort*)(ws + O_T2H);
    ushort* T2L = (ushort*)(ws + O_T2L);
    for (int nl = 0; nl < NCH1; ++nl) {
      float xr[L4];
      *(float4*)&xr[0] = *(const float4*)(xs + c*(NCH1*L4) + nl*L4);
      *(float4*)&xr[4] = *(const float4*)(xs + c*(NCH1*L4) + nl*L4 + 4);
      *(float4*)&xr[8] = *(const float4*)(xs + c*(NCH1*L4) + nl*L4 + 8);
      float tvp[4];
      #pragma unroll
      for (int i = 0; i < 4; ++i) {
        float a = 0.f;
        #pragma unroll
        for (int j = 0; j < L4; ++j) a += fcs[nl*(CQ*L4) + (q0+i)*L4 + j] * xr[j];
        tvp[i] = a;
        vals[i][nl] = a;
      }
      uint hw0, lw0, hw1, lw1;
      split2(tvp[0], tvp[1], hw0, lw0);
      split2(tvp[2], tvp[3], hw1, lw1);
      size_t off2 = ((size_t)b*NN + n0 + nl)*1024 + t*4;   // ushort index
      *(uint2*)(T2H + off2) = make_uint2(hw0, hw1);
      *(uint2*)(T2L + off2) = make_uint2(lw0, lw1);
    }
    ushort* TH = (ushort*)(ws + O_TH);
    ushort* TL = (ushort*)(ws + O_TL);
    #pragma unroll
    for (int i = 0; i < 4; ++i) {
      int m = c*16 + q0 + i;
      uint hw[4], lw[4];
      #pragma unroll
      for (int jj = 0; jj < 4; ++jj)
        split2(vals[i][2*jj], vals[i][2*jj+1], hw[jj], lw[jj]);
      size_t off = ((size_t)b*1024 + m)*NN + n0;   // ushort index
      *(uint4*)(TH + off) = make_uint4(hw[0], hw[1], hw[2], hw[3]);
      *(uint4*)(TL + off) = make_uint4(lw[0], lw[1], lw[2], lw[3]);
    }
  }
}

// K1b (merged): block 0 computes l2inv; all 16 blocks convert Flt planes.
__global__ __launch_bounds__(256) void k1b_l2flt(float* __restrict__ ws) {
  int t = threadIdx.x;
  if (blockIdx.x == 0) {
    __shared__ float s[B*CQ];
    if (t < B*CQ) s[t] = sqrtf(ws[O_XX + t]) * sqrtf(ws[O_YY + t]);
    __syncthreads();
    if (t < B) {
      float sum = 0.f;
      #pragma unroll
      for (int q = 0; q < CQ; ++q) sum += s[t*CQ + q];
      ws[O_L2 + t] = 1.0f / sum;
    }
  }
  int idx = blockIdx.x*256 + t;             // 0..4095 = b*512 + k
  int b = idx >> 9, k = idx & 511;
  const float* fl = ws + O_FL + (size_t)b*CQ*NN + k;
  ushort h[16], l[16];
  #pragma unroll
  for (int q = 0; q < CQ; ++q) {
    float v = fl[(size_t)q*NN];
    uint u = __float_as_uint(v);
    uint hh = u >> 16;
    float r = v - __uint_as_float(hh << 16);
    h[q] = (ushort)hh;
    l[q] = (ushort)(__float_as_uint(r) >> 16);
  }
  ushort* FH  = (ushort*)(ws + O_FLTH) + (size_t)idx*16;
  ushort* FLo = (ushort*)(ws + O_FLTL) + (size_t)idx*16;
  *(uint4*)(FH)      = *(uint4*)&h[0];
  *(uint4*)(FH + 8)  = *(uint4*)&h[8];
  *(uint4*)(FLo)     = *(uint4*)&l[0];
  *(uint4*)(FLo + 8) = *(uint4*)&l[8];
}

// K2 (pass 1, MFMA 32x32x16 split-bf16), XCD-swizzled: b = id & 7 so all
// blocks of a batch share an XCD (working set ~2.1 MB < 4 MB L2).
__global__ __launch_bounds__(256, 4) void k2_mfma(float* __restrict__ ws) {
  int id = blockIdx.x;              // (nch*2 + kh)*8 + b
  int b = id & 7;
  int rest = id >> 3;
  int kh = rest & 1;
  int nch = rest >> 1;
  int t = threadIdx.x;
  int w = t >> 6, lane = t & 63;
  int col = lane & 31, half = lane >> 5;
  float l2inv = ws[O_L2 + b];
  const ushort* FltH = (const ushort*)(ws + O_FLTH);
  const ushort* FltL = (const ushort*)(ws + O_FLTL);
  short8 bhf[2], blf[2];
  int kcol[2];
  #pragma unroll
  for (int kt = 0; kt < 2; ++kt) {
    kcol[kt] = kh*256 + w*64 + kt*32 + col;
    size_t off = ((size_t)(b*NN + kcol[kt]))*16 + half*8;
    bhf[kt] = *(const short8*)(FltH + off);
    blf[kt] = *(const short8*)(FltL + off);
  }
  const ushort* T2H = (const ushort*)(ws + O_T2H) + ((size_t)b*NN + nch*8)*1024;
  const ushort* T2L = (const ushort*)(ws + O_T2L) + ((size_t)b*NN + nch*8)*1024;
  ushort* AH = (ushort*)(ws + O_AH) + ((size_t)b*NN + nch*8)*NN;
  ushort* AL = (ushort*)(ws + O_AL) + ((size_t)b*NN + nch*8)*NN;

  for (int i = 0; i < 8; ++i) {
    short8 ah[2], al[2];
    #pragma unroll
    for (int ct = 0; ct < 2; ++ct) {
      size_t off = (size_t)i*1024 + (ct*32 + col)*16 + half*8;
      ah[ct] = *(const short8*)(T2H + off);
      al[ct] = *(const short8*)(T2L + off);
    }
    floatx16 acc[2][2];
    #pragma unroll
    for (int ct = 0; ct < 2; ++ct)
      #pragma unroll
      for (int kt = 0; kt < 2; ++kt) {
        floatx16 a = {0.f,0.f,0.f,0.f,0.f,0.f,0.f,0.f,
                      0.f,0.f,0.f,0.f,0.f,0.f,0.f,0.f};
        a = __builtin_amdgcn_mfma_f32_32x32x16_bf16(ah[ct], bhf[kt], a, 0, 0, 0);
        a = __builtin_amdgcn_mfma_f32_32x32x16_bf16(ah[ct], blf[kt], a, 0, 0, 0);
        a = __builtin_amdgcn_mfma_f32_32x32x16_bf16(al[ct], bhf[kt], a, 0, 0, 0);
        acc[ct][kt] = a;
      }
    #pragma unroll
    for (int kt = 0; kt < 2; ++kt) {
      float m = acc[0][kt][0];
      #pragma unroll
      for (int ct = 0; ct < 2; ++ct)
        #pragma unroll
        for (int rg = 0; rg < 16; ++rg)
          if (ct + rg) m = fmaxf(m, acc[ct][kt][rg]);
      m = fmaxf(m, __shfl_xor(m, 32));
      float av = fmaxf(tanhf(m*l2inv), 0.f);
      uint u = __float_as_uint(av);
      uint hh = u >> 16;
      float r = av - __uint_as_float(hh << 16);
      ushort lv = (ushort)(__float_as_uint(r) >> 16);
      if (half == 0) {
        AH[(size_t)i*NN + kcol[kt]] = (ushort)hh;
        AL[(size_t)i*NN + kcol[kt]] = lv;
      }
    }
  }
}

// K3 (pass 2, MFMA split-bf16, LDS-staged R11 structure), XCD-swizzled:
// b = id & 7 -> all 64 blocks of a batch on one XCD (3 MB < 4 MB L2).
__global__ __launch_bounds__(256, 2) void k3_mfma(float* __restrict__ ws) {
  int id = blockIdx.x;             // (mbb*8 + kb)*8 + b
  int b = id & 7;
  int rest = id >> 3;
  int kb = rest & 7;
  int mbb = rest >> 3;
  int t = threadIdx.x;
  int lane = t & 63;
  int w = t >> 6;
  int mw = w >> 1, kw = w & 1;
  int row = lane & 15, quad = lane >> 4;

  __shared__ __align__(16) ushort Ah[128*32];
  __shared__ __align__(16) ushort Al[128*32];
  __shared__ __align__(16) ushort Bh[64*32];
  __shared__ __align__(16) ushort Bl[64*32];

  const ushort* TH = (const ushort*)(ws + O_TH) + ((size_t)b*1024 + mbb*128)*NN;
  const ushort* TL = (const ushort*)(ws + O_TL) + ((size_t)b*1024 + mbb*128)*NN;
  const ushort* AHp = (const ushort*)(ws + O_AH) + ((size_t)b*NN + kb*64)*NN;
  const ushort* ALp = (const ushort*)(ws + O_AL) + ((size_t)b*NN + kb*64)*NN;

  floatx4 acc[4][2];
  #pragma unroll
  for (int i = 0; i < 4; ++i)
    #pragma unroll
    for (int j = 0; j < 2; ++j) acc[i][j] = (floatx4){0.f, 0.f, 0.f, 0.f};

  for (int ksx = 0; ksx < 16; ++ksx) {
    int p0 = ksx*32;
    __syncthreads();
    #pragma unroll
    for (int i = 0; i < 2; ++i) {       // A: 128 rows x 32 n, hi+lo
      int f = t + 256*i;
      int m = f >> 2, seg = (f & 3) * 8;
      *(uint4*)(Ah + m*32 + seg) = *(const uint4*)(TH + (size_t)m*NN + p0 + seg);
      *(uint4*)(Al + m*32 + seg) = *(const uint4*)(TL + (size_t)m*NN + p0 + seg);
    }
    {                                   // B: 64 rows x 32 n, hi+lo
      int j = t >> 2, seg = (t & 3) * 8;
      *(uint4*)(Bh + j*32 + seg) = *(const uint4*)(AHp + (size_t)j*NN + p0 + seg);
      *(uint4*)(Bl + j*32 + seg) = *(const uint4*)(ALp + (size_t)j*NN + p0 + seg);
    }
    __syncthreads();
    short8 bh[2], bl[2];
    #pragma unroll
    for (int kt = 0; kt < 2; ++kt) {
      int jrow = kw*32 + kt*16 + row;
      bh[kt] = *(const short8*)(Bh + jrow*32 + quad*8);
      bl[kt] = *(const short8*)(Bl + jrow*32 + quad*8);
    }
    #pragma unroll
    for (int mt = 0; mt < 4; ++mt) {
      int mrow = mw*64 + mt*16 + row;
      short8 ah = *(const short8*)(Ah + mrow*32 + quad*8);
      short8 al = *(const short8*)(Al + mrow*32 + quad*8);
      #pragma unroll
      for (int kt = 0; kt < 2; ++kt) {
        acc[mt][kt] = __builtin_amdgcn_mfma_f32_16x16x32_bf16(ah, bh[kt], acc[mt][kt], 0, 0, 0);
        acc[mt][kt] = __builtin_amdgcn_mfma_f32_16x16x32_bf16(ah, bl[kt], acc[mt][kt], 0, 0, 0);
        acc[mt][kt] = __builtin_amdgcn_mfma_f32_16x16x32_bf16(al, bh[kt], acc[mt][kt], 0, 0, 0);
      }
    }
  }
  float l2inv = ws[O_L2 + b];
  const float* flb = ws + O_FL + (size_t)b*CQ*NN;
  float fl[2][4];
  #pragma unroll
  for (int kt = 0; kt < 2; ++kt) {
    int kcol = kb*64 + kw*32 + kt*16 + row;
    #pragma unroll
    for (int rg = 0; rg < 4; ++rg)
      fl[kt][rg] = flb[(size_t)(quad*4 + rg)*NN + kcol];
  }
  #pragma unroll
  for (int mt = 0; mt < 4; ++mt) {
    int c = mbb*8 + mw*4 + mt;
    #pragma unroll
    for (int kt = 0; kt < 2; ++kt) {
      float s = fl[kt][0]*acc[mt][kt][0] + fl[kt][1]*acc[mt][kt][1]
              + fl[kt][2]*acc[mt][kt][2] + fl[kt][3]*acc[mt][kt][3];
      s += __shfl_xor(s, 32);
      s += __shfl_xor(s, 16);
      if (quad == 0) {
        int kcol = kb*64 + kw*32 + kt*16 + row;
        ws[O_XG + ((size_t)b*C4 + c)*NN + kcol] = s * l2inv;
      }
    }
  }
}

// K4: Fg = W_gcn xg + b_gcn
__global__ __launch_bounds__(256) void k4_out(const float* __restrict__ Wg,
                                              const float* __restrict__ bg,
                                              const float* __restrict__ ws,
                                              float* __restrict__ out) {
  int blk = blockIdx.x;             // b*4 + kc
  int b = blk >> 2, kc = blk & 3;
  int t = threadIdx.x;
  __shared__ float xg[C4][KT+1];
  __shared__ float wg[C4*C4];
  for (int e = t; e < C4*C4; e += 256) wg[e] = Wg[e];
  for (int e = t; e < C4*KT; e += 256) {
    int c = e >> 7, kk = e & (KT-1);
    xg[c][kk] = ws[O_XG + ((size_t)(b*C4 + c))*NN + kc*KT + kk];
  }
  __syncthreads();
  int kk = t & (KT-1);
  int ohalf = t >> 7;
  for (int oi = 0; oi < 32; ++oi) {
    int o = ohalf*32 + oi;
    float acc = bg[o];
    #pragma unroll
    for (int c = 0; c < C4; ++c) acc += wg[o*C4 + c] * xg[c][kk];
    out[((size_t)(b*C4 + o))*NN + kc*KT + kk] = acc;
  }
}

extern "C" void kernel_launch(void* const* d_in, const int* in_sizes, int n_in,
                              void* d_out, int out_size, void* d_ws, size_t ws_size,
                              hipStream_t stream) {
  const float* x  = (const float*)d_in[0];
  const float* Wc = (const float*)d_in[1];
  const float* bc = (const float*)d_in[2];
  const float* Wg = (const float*)d_in[3];
  const float* bg = (const float*)d_in[4];
  float* ws  = (float*)d_ws;
  float* out = (float*)d_out;

  hipMemsetAsync(ws + O_XX, 0, (2*B*CQ + 16)*sizeof(float), stream);

  k1_fc    <<<B*64,   256, 0, stream>>>(x, Wc, bc, ws);
  k1b_l2flt<<<16,     256, 0, stream>>>(ws);
  k2_mfma  <<<B*128,  256, 0, stream>>>(ws);
  k3_mfma  <<<B*64,   256, 0, stream>>>(ws);
  k4_out   <<<B*4,    256, 0, stream>>>(Wg, bg, ws, out);
}

// Round 15
// 152.810 us; speedup vs baseline: 1.1478x; 1.0060x over previous
//
#include <hip/hip_runtime.h>
#include <hip/hip_bf16.h>
#include <math.h>

// Problem constants
#define B    8
#define C4   64
#define CQ   16
#define NN   512
#define L4   12
#define KT   128          // k-tile in final kernel
#define XSP  100          // padded LDS row stride for x (96 -> 100, bank fix)

// workspace layout (float offsets)
#define O_TH   0                                   // Thi bf16 [b][m][n]      2097152
#define O_TL   (O_TH + (size_t)B*1024*NN/2)        // Tlo bf16 [b][m][n]      2097152
#define O_T2H  (O_TL + (size_t)B*1024*NN/2)        // Thi bf16 [b][n][m]      2097152
#define O_T2L  (O_T2H + (size_t)B*NN*1024/2)       // Tlo bf16 [b][n][m]      2097152
#define O_FL   (O_T2L + (size_t)B*NN*1024/2)       // Fl[b][q][k] fp32          65536
#define O_FLTH (O_FL + (size_t)B*CQ*NN)            // Flt hi bf16 [b][k][16]    32768
#define O_FLTL (O_FLTH + (size_t)B*NN*16/2)        // Flt lo bf16 [b][k][16]    32768
#define O_XX   (O_FLTL + (size_t)B*NN*16/2)        // [B][CQ]                     128
#define O_YY   (O_XX + B*CQ)                       //                             128
#define O_L2   (O_YY + B*CQ)                       // [B] 1/l2 (+pad)              16
#define O_AH   (O_L2 + 16)                         // Ahi bf16 [b][n][k]      1048576
#define O_AL   (O_AH + (size_t)B*NN*NN/2)          // Alo bf16 [b][n][k]      1048576
#define O_XG   (O_AL + (size_t)B*NN*NN/2)          // xg[b][c][k] fp32         262144
#define O_FCG  (O_XG + (size_t)B*C4*NN)            // Fc scratch [blk][1536]   786432

typedef __attribute__((ext_vector_type(8))) short short8;
typedef __attribute__((ext_vector_type(4))) float floatx4;
typedef __attribute__((ext_vector_type(16))) float floatx16;

__device__ inline void split2(float x0, float x1, uint& hw, uint& lw) {
  uint u0 = __float_as_uint(x0), u1 = __float_as_uint(x1);
  uint h0 = u0 >> 16, h1 = u1 >> 16;
  float r0 = x0 - __uint_as_float(h0 << 16);
  float r1 = x1 - __uint_as_float(h1 << 16);
  hw = h0 | (h1 << 16);
  lw = (__float_as_uint(r0) >> 16) | ((__float_as_uint(r1) >> 16) << 16);
}

// K1a: Fc = Wc x + bc, Fl, norms; Fc -> global scratch. XCD-swizzled.
__global__ __launch_bounds__(256) void k1a_fc(const float* __restrict__ x,
                                              const float* __restrict__ Wc,
                                              const float* __restrict__ bc,
                                              float* __restrict__ ws) {
  int id = blockIdx.x;
  int b = id & 7;
  int nch = id >> 3;
  int n0 = nch * 8;
  int t = threadIdx.x;
  __shared__ __align__(16) float xs[C4*XSP];       // [c][nl*12+j], padded
  __shared__ float wcs[CQ*65];
  __shared__ float bcs[CQ];
  __shared__ __align__(16) float fcs[8*CQ*L4];     // [nl][q][j] 1536

  for (int e = t; e < CQ*C4; e += 256) {
    int q = e >> 6, c = e & 63;
    wcs[q*65 + c] = Wc[e];
  }
  if (t < CQ) bcs[t] = bc[t];
  const float* xb = x + (size_t)b*C4*NN*L4 + (size_t)n0*L4;
  for (int f = t; f < C4*24; f += 256) {           // 24 float4s per c
    int c = f / 24, r = f - c*24;
    float4 v = *(const float4*)(xb + (size_t)c*NN*L4 + r*4);
    *(float4*)(xs + c*XSP + r*4) = v;
  }
  __syncthreads();
  // Fc: thread owns q = t&15, slots nj = (t>>4) + 16*i (i<6)
  {
    int q = t & 15, slot = t >> 4;
    float accv[6];
    #pragma unroll
    for (int i = 0; i < 6; ++i) accv[i] = bcs[q];
    for (int c = 0; c < C4; ++c) {
      float wv = wcs[q*65 + c];
      const float* xc = xs + c*XSP;
      #pragma unroll
      for (int i = 0; i < 6; ++i) accv[i] += wv * xc[slot + 16*i];
    }
    #pragma unroll
    for (int i = 0; i < 6; ++i) {
      int nj = slot + 16*i;
      int nl = nj / L4, j = nj - nl*L4;
      fcs[nl*(CQ*L4) + q*L4 + j] = accv[i];
      if (j == L4-1) ws[O_FL + ((size_t)b*CQ + q)*NN + n0 + nl] = accv[i];
    }
  }
  __syncthreads();
  if (t < CQ) {
    float yy = 0.f, xx = 0.f;
    for (int nl = 0; nl < 8; ++nl) {
      #pragma unroll
      for (int j = 0; j < L4; ++j) { float v = fcs[nl*(CQ*L4) + t*L4 + j]; yy += v*v; }
      float w = fcs[nl*(CQ*L4) + t*L4 + (L4-1)];
      xx += w*w;
    }
    atomicAdd(ws + O_YY + b*CQ + t, yy);
    atomicAdd(ws + O_XX + b*CQ + t, xx);
  }
  // dump Fc to global scratch (contiguous)
  float* fcg = ws + O_FCG + (size_t)(b*64 + nch)*1536;
  for (int f = t; f < 384; f += 256)
    *(float4*)(fcg + f*4) = *(const float4*)(fcs + f*4);
}

// K1t: T planes (TH/TL [m][n], T2H/T2L [n][m]) from x + Fc scratch.
__global__ __launch_bounds__(256, 4) void k1t_T(const float* __restrict__ x,
                                                float* __restrict__ ws) {
  int id = blockIdx.x;
  int b = id & 7;
  int nch = id >> 3;
  int n0 = nch * 8;
  int t = threadIdx.x;
  __shared__ __align__(16) float xs[C4*XSP];
  __shared__ __align__(16) float fcs[8*CQ*L4];
  const float* xb = x + (size_t)b*C4*NN*L4 + (size_t)n0*L4;
  for (int f = t; f < C4*24; f += 256) {
    int c = f / 24, r = f - c*24;
    float4 v = *(const float4*)(xb + (size_t)c*NN*L4 + r*4);
    *(float4*)(xs + c*XSP + r*4) = v;
  }
  {
    const float* fcg = ws + O_FCG + (size_t)(b*64 + nch)*1536;
    for (int f = t; f < 384; f += 256)
      *(float4*)(fcs + f*4) = *(const float4*)(fcg + f*4);
  }
  __syncthreads();
  int c = t >> 2, q0 = (t & 3) * 4;
  float vals[4][8];
  ushort* T2H = (ushort*)(ws + O_T2H);
  ushort* T2L = (ushort*)(ws + O_T2L);
  for (int nl = 0; nl < 8; ++nl) {
    float xr[L4];
    *(float4*)&xr[0] = *(const float4*)(xs + c*XSP + nl*L4);
    *(float4*)&xr[4] = *(const float4*)(xs + c*XSP + nl*L4 + 4);
    *(float4*)&xr[8] = *(const float4*)(xs + c*XSP + nl*L4 + 8);
    float tvp[4];
    #pragma unroll
    for (int i = 0; i < 4; ++i) {
      const float* fq = fcs + nl*(CQ*L4) + (q0+i)*L4;
      float a = 0.f;
      #pragma unroll
      for (int j = 0; j < L4; ++j) a += fq[j] * xr[j];
      tvp[i] = a;
      vals[i][nl] = a;
    }
    uint hw0, lw0, hw1, lw1;
    split2(tvp[0], tvp[1], hw0, lw0);
    split2(tvp[2], tvp[3], hw1, lw1);
    size_t off2 = ((size_t)b*NN + n0 + nl)*1024 + t*4;
    *(uint2*)(T2H + off2) = make_uint2(hw0, hw1);
    *(uint2*)(T2L + off2) = make_uint2(lw0, lw1);
  }
  ushort* TH = (ushort*)(ws + O_TH);
  ushort* TL = (ushort*)(ws + O_TL);
  #pragma unroll
  for (int i = 0; i < 4; ++i) {
    int m = c*16 + q0 + i;
    uint hw[4], lw[4];
    #pragma unroll
    for (int jj = 0; jj < 4; ++jj)
      split2(vals[i][2*jj], vals[i][2*jj+1], hw[jj], lw[jj]);
    size_t off = ((size_t)b*1024 + m)*NN + n0;
    *(uint4*)(TH + off) = make_uint4(hw[0], hw[1], hw[2], hw[3]);
    *(uint4*)(TL + off) = make_uint4(lw[0], lw[1], lw[2], lw[3]);
  }
}

// K1b (merged): block 0 computes l2inv; all 16 blocks convert Flt planes.
__global__ __launch_bounds__(256) void k1b_l2flt(float* __restrict__ ws) {
  int t = threadIdx.x;
  if (blockIdx.x == 0) {
    __shared__ float s[B*CQ];
    if (t < B*CQ) s[t] = sqrtf(ws[O_XX + t]) * sqrtf(ws[O_YY + t]);
    __syncthreads();
    if (t < B) {
      float sum = 0.f;
      #pragma unroll
      for (int q = 0; q < CQ; ++q) sum += s[t*CQ + q];
      ws[O_L2 + t] = 1.0f / sum;
    }
  }
  int idx = blockIdx.x*256 + t;             // 0..4095 = b*512 + k
  int b = idx >> 9, k = idx & 511;
  const float* fl = ws + O_FL + (size_t)b*CQ*NN + k;
  ushort h[16], l[16];
  #pragma unroll
  for (int q = 0; q < CQ; ++q) {
    float v = fl[(size_t)q*NN];
    uint u = __float_as_uint(v);
    uint hh = u >> 16;
    float r = v - __uint_as_float(hh << 16);
    h[q] = (ushort)hh;
    l[q] = (ushort)(__float_as_uint(r) >> 16);
  }
  ushort* FH  = (ushort*)(ws + O_FLTH) + (size_t)idx*16;
  ushort* FLo = (ushort*)(ws + O_FLTL) + (size_t)idx*16;
  *(uint4*)(FH)      = *(uint4*)&h[0];
  *(uint4*)(FH + 8)  = *(uint4*)&h[8];
  *(uint4*)(FLo)     = *(uint4*)&l[0];
  *(uint4*)(FLo + 8) = *(uint4*)&l[8];
}

// K2 (pass 1, MFMA 32x32x16 split-bf16), XCD-swizzled (b = id & 7).
__global__ __launch_bounds__(256, 4) void k2_mfma(float* __restrict__ ws) {
  int id = blockIdx.x;              // (nch*2 + kh)*8 + b
  int b = id & 7;
  int rest = id >> 3;
  int kh = rest & 1;
  int nch = rest >> 1;
  int t = threadIdx.x;
  int w = t >> 6, lane = t & 63;
  int col = lane & 31, half = lane >> 5;
  float l2inv = ws[O_L2 + b];
  const ushort* FltH = (const ushort*)(ws + O_FLTH);
  const ushort* FltL = (const ushort*)(ws + O_FLTL);
  short8 bhf[2], blf[2];
  int kcol[2];
  #pragma unroll
  for (int kt = 0; kt < 2; ++kt) {
    kcol[kt] = kh*256 + w*64 + kt*32 + col;
    size_t off = ((size_t)(b*NN + kcol[kt]))*16 + half*8;
    bhf[kt] = *(const short8*)(FltH + off);
    blf[kt] = *(const short8*)(FltL + off);
  }
  const ushort* T2H = (const ushort*)(ws + O_T2H) + ((size_t)b*NN + nch*8)*1024;
  const ushort* T2L = (const ushort*)(ws + O_T2L) + ((size_t)b*NN + nch*8)*1024;
  ushort* AH = (ushort*)(ws + O_AH) + ((size_t)b*NN + nch*8)*NN;
  ushort* AL = (ushort*)(ws + O_AL) + ((size_t)b*NN + nch*8)*NN;

  for (int i = 0; i < 8; ++i) {
    short8 ah[2], al[2];
    #pragma unroll
    for (int ct = 0; ct < 2; ++ct) {
      size_t off = (size_t)i*1024 + (ct*32 + col)*16 + half*8;
      ah[ct] = *(const short8*)(T2H + off);
      al[ct] = *(const short8*)(T2L + off);
    }
    floatx16 acc[2][2];
    #pragma unroll
    for (int ct = 0; ct < 2; ++ct)
      #pragma unroll
      for (int kt = 0; kt < 2; ++kt) {
        floatx16 a = {0.f,0.f,0.f,0.f,0.f,0.f,0.f,0.f,
                      0.f,0.f,0.f,0.f,0.f,0.f,0.f,0.f};
        a = __builtin_amdgcn_mfma_f32_32x32x16_bf16(ah[ct], bhf[kt], a, 0, 0, 0);
        a = __builtin_amdgcn_mfma_f32_32x32x16_bf16(ah[ct], blf[kt], a, 0, 0, 0);
        a = __builtin_amdgcn_mfma_f32_32x32x16_bf16(al[ct], bhf[kt], a, 0, 0, 0);
        acc[ct][kt] = a;
      }
    #pragma unroll
    for (int kt = 0; kt < 2; ++kt) {
      float m = acc[0][kt][0];
      #pragma unroll
      for (int ct = 0; ct < 2; ++ct)
        #pragma unroll
        for (int rg = 0; rg < 16; ++rg)
          if (ct + rg) m = fmaxf(m, acc[ct][kt][rg]);
      m = fmaxf(m, __shfl_xor(m, 32));
      float av = fmaxf(tanhf(m*l2inv), 0.f);
      uint u = __float_as_uint(av);
      uint hh = u >> 16;
      float r = av - __uint_as_float(hh << 16);
      ushort lv = (ushort)(__float_as_uint(r) >> 16);
      if (half == 0) {
        AH[(size_t)i*NN + kcol[kt]] = (ushort)hh;
        AL[(size_t)i*NN + kcol[kt]] = lv;
      }
    }
  }
}

// K3 (pass 2, MFMA split-bf16, LDS-staged), XCD-swizzled (b = id & 7).
__global__ __launch_bounds__(256, 2) void k3_mfma(float* __restrict__ ws) {
  int id = blockIdx.x;             // (mbb*8 + kb)*8 + b
  int b = id & 7;
  int rest = id >> 3;
  int kb = rest & 7;
  int mbb = rest >> 3;
  int t = threadIdx.x;
  int lane = t & 63;
  int w = t >> 6;
  int mw = w >> 1, kw = w & 1;
  int row = lane & 15, quad = lane >> 4;

  __shared__ __align__(16) ushort Ah[128*32];
  __shared__ __align__(16) ushort Al[128*32];
  __shared__ __align__(16) ushort Bh[64*32];
  __shared__ __align__(16) ushort Bl[64*32];

  const ushort* TH = (const ushort*)(ws + O_TH) + ((size_t)b*1024 + mbb*128)*NN;
  const ushort* TL = (const ushort*)(ws + O_TL) + ((size_t)b*1024 + mbb*128)*NN;
  const ushort* AHp = (const ushort*)(ws + O_AH) + ((size_t)b*NN + kb*64)*NN;
  const ushort* ALp = (const ushort*)(ws + O_AL) + ((size_t)b*NN + kb*64)*NN;

  floatx4 acc[4][2];
  #pragma unroll
  for (int i = 0; i < 4; ++i)
    #pragma unroll
    for (int j = 0; j < 2; ++j) acc[i][j] = (floatx4){0.f, 0.f, 0.f, 0.f};

  for (int ksx = 0; ksx < 16; ++ksx) {
    int p0 = ksx*32;
    __syncthreads();
    #pragma unroll
    for (int i = 0; i < 2; ++i) {       // A: 128 rows x 32 n, hi+lo
      int f = t + 256*i;
      int m = f >> 2, seg = (f & 3) * 8;
      *(uint4*)(Ah + m*32 + seg) = *(const uint4*)(TH + (size_t)m*NN + p0 + seg);
      *(uint4*)(Al + m*32 + seg) = *(const uint4*)(TL + (size_t)m*NN + p0 + seg);
    }
    {                                   // B: 64 rows x 32 n, hi+lo
      int j = t >> 2, seg = (t & 3) * 8;
      *(uint4*)(Bh + j*32 + seg) = *(const uint4*)(AHp + (size_t)j*NN + p0 + seg);
      *(uint4*)(Bl + j*32 + seg) = *(const uint4*)(ALp + (size_t)j*NN + p0 + seg);
    }
    __syncthreads();
    short8 bh[2], bl[2];
    #pragma unroll
    for (int kt = 0; kt < 2; ++kt) {
      int jrow = kw*32 + kt*16 + row;
      bh[kt] = *(const short8*)(Bh + jrow*32 + quad*8);
      bl[kt] = *(const short8*)(Bl + jrow*32 + quad*8);
    }
    #pragma unroll
    for (int mt = 0; mt < 4; ++mt) {
      int mrow = mw*64 + mt*16 + row;
      short8 ah = *(const short8*)(Ah + mrow*32 + quad*8);
      short8 al = *(const short8*)(Al + mrow*32 + quad*8);
      #pragma unroll
      for (int kt = 0; kt < 2; ++kt) {
        acc[mt][kt] = __builtin_amdgcn_mfma_f32_16x16x32_bf16(ah, bh[kt], acc[mt][kt], 0, 0, 0);
        acc[mt][kt] = __builtin_amdgcn_mfma_f32_16x16x32_bf16(ah, bl[kt], acc[mt][kt], 0, 0, 0);
        acc[mt][kt] = __builtin_amdgcn_mfma_f32_16x16x32_bf16(al, bh[kt], acc[mt][kt], 0, 0, 0);
      }
    }
  }
  float l2inv = ws[O_L2 + b];
  const float* flb = ws + O_FL + (size_t)b*CQ*NN;
  float fl[2][4];
  #pragma unroll
  for (int kt = 0; kt < 2; ++kt) {
    int kcol = kb*64 + kw*32 + kt*16 + row;
    #pragma unroll
    for (int rg = 0; rg < 4; ++rg)
      fl[kt][rg] = flb[(size_t)(quad*4 + rg)*NN + kcol];
  }
  #pragma unroll
  for (int mt = 0; mt < 4; ++mt) {
    int c = mbb*8 + mw*4 + mt;
    #pragma unroll
    for (int kt = 0; kt < 2; ++kt) {
      float s = fl[kt][0]*acc[mt][kt][0] + fl[kt][1]*acc[mt][kt][1]
              + fl[kt][2]*acc[mt][kt][2] + fl[kt][3]*acc[mt][kt][3];
      s += __shfl_xor(s, 32);
      s += __shfl_xor(s, 16);
      if (quad == 0) {
        int kcol = kb*64 + kw*32 + kt*16 + row;
        ws[O_XG + ((size_t)b*C4 + c)*NN + kcol] = s * l2inv;
      }
    }
  }
}

// K4: Fg = W_gcn xg + b_gcn
__global__ __launch_bounds__(256) void k4_out(const float* __restrict__ Wg,
                                              const float* __restrict__ bg,
                                              const float* __restrict__ ws,
                                              float* __restrict__ out) {
  int blk = blockIdx.x;             // b*4 + kc
  int b = blk >> 2, kc = blk & 3;
  int t = threadIdx.x;
  __shared__ float xg[C4][KT+1];
  __shared__ float wg[C4*C4];
  for (int e = t; e < C4*C4; e += 256) wg[e] = Wg[e];
  for (int e = t; e < C4*KT; e += 256) {
    int c = e >> 7, kk = e & (KT-1);
    xg[c][kk] = ws[O_XG + ((size_t)(b*C4 + c))*NN + kc*KT + kk];
  }
  __syncthreads();
  int kk = t & (KT-1);
  int ohalf = t >> 7;
  for (int oi = 0; oi < 32; ++oi) {
    int o = ohalf*32 + oi;
    float acc = bg[o];
    #pragma unroll
    for (int c = 0; c < C4; ++c) acc += wg[o*C4 + c] * xg[c][kk];
    out[((size_t)(b*C4 + o))*NN + kc*KT + kk] = acc;
  }
}

extern "C" void kernel_launch(void* const* d_in, const int* in_sizes, int n_in,
                              void* d_out, int out_size, void* d_ws, size_t ws_size,
                              hipStream_t stream) {
  const float* x  = (const float*)d_in[0];
  const float* Wc = (const float*)d_in[1];
  const float* bc = (const float*)d_in[2];
  const float* Wg = (const float*)d_in[3];
  const float* bg = (const float*)d_in[4];
  float* ws  = (float*)d_ws;
  float* out = (float*)d_out;

  hipMemsetAsync(ws + O_XX, 0, (2*B*CQ + 16)*sizeof(float), stream);

  k1a_fc   <<<B*64,   256, 0, stream>>>(x, Wc, bc, ws);
  k1b_l2flt<<<16,     256, 0, stream>>>(ws);
  k1t_T    <<<B*64,   256, 0, stream>>>(x, ws);
  k2_mfma  <<<B*128,  256, 0, stream>>>(ws);
  k3_mfma  <<<B*64,   256, 0, stream>>>(ws);
  k4_out   <<<B*4,    256, 0, stream>>>(Wg, bg, ws, out);
}